// Round 8
// baseline (540.210 us; speedup 1.0000x reference)
//
#include <hip/hip_runtime.h>
#include <stdint.h>

// RNN ensemble: M=2048 models, N=128, A=4 conds, 5 phases x 50 steps.
// Block = 1 model, 4 waves. Wave w owns rows 32w..32w+31 (2 M-tiles).
// pre[128x4] = W @ r via mfma_f32_16x16x32_bf16, hi/lo bf16 split:
//   B cols 0-3 = rhi (4 conds), cols 4-7 = rlo; acc chains Whi@B then Wlo@B
//   => comb = col_c + col_{c^4} (shfl_xor 4) = cc + W@rhi + W@rlo.
// R8: W fragments PINNED IN AGPRS via inline-asm MFMA with "a" A-operand
// (14 of 16 frags; 56 AGPRs). Final MFMA per chain is the builtin with its
// A (wlo[*][3]) in VGPRs, so the compiler emits the MFMA->VALU hazard
// handling for the acc reads that follow (asm->builtin C-chaining is the
// HW-pipelined accumulate pattern, no nops needed). amdgpu_waves_per_eu(4,4)
// pins the allocator at 4 waves/EU; R7's 64-VGPR+spill pathology (101 MB
// scratch writes) should vanish. rsD/rsR unified (never live together).

typedef __attribute__((ext_vector_type(8))) short bf16x8;
typedef __attribute__((ext_vector_type(4))) float f32x4;

struct __align__(16) Smem {
  unsigned short bfrag[2][4][4][8][8]; // [parity][q][kg][col][e] bf16, 4KB
  float nbuf[2][128];                  // [substep][row] 0.02-scaled noise, 1KB
  uint2 skeys[250];
  float red[4][4][2];                  // [wave][cond][o]
};

__device__ __forceinline__ void tfround(uint32_t& x0, uint32_t& x1, const int r) {
  x0 += x1;
  x1 = (x1 << r) | (x1 >> (32 - r));
  x1 ^= x0;
}

// JAX threefry2x32 (20 rounds)
__device__ __forceinline__ uint2 threefry(uint32_t k0, uint32_t k1, uint32_t c0, uint32_t c1) {
  uint32_t k2 = k0 ^ k1 ^ 0x1BD11BDAu;
  uint32_t x0 = c0 + k0, x1 = c1 + k1;
  tfround(x0,x1,13); tfround(x0,x1,15); tfround(x0,x1,26); tfround(x0,x1,6);
  x0 += k1; x1 += k2 + 1u;
  tfround(x0,x1,17); tfround(x0,x1,29); tfround(x0,x1,16); tfround(x0,x1,24);
  x0 += k2; x1 += k0 + 2u;
  tfround(x0,x1,13); tfround(x0,x1,15); tfround(x0,x1,26); tfround(x0,x1,6);
  x0 += k0; x1 += k1 + 3u;
  tfround(x0,x1,17); tfround(x0,x1,29); tfround(x0,x1,16); tfround(x0,x1,24);
  x0 += k1; x1 += k2 + 4u;
  tfround(x0,x1,13); tfround(x0,x1,15); tfround(x0,x1,26); tfround(x0,x1,6);
  x0 += k2; x1 += k0 + 5u;
  return make_uint2(x0, x1);
}

__device__ __forceinline__ float unit_from_bits(uint32_t bits) {
  return __uint_as_float((bits >> 9) | 0x3f800000u) - 1.0f;
}

__device__ __forceinline__ unsigned short f2bf(float f) {
  uint32_t u = __float_as_uint(f);
  uint32_t r = u + 0x7fffu + ((u >> 16) & 1u);   // RNE (non-NaN inputs)
  return (unsigned short)(r >> 16);
}
__device__ __forceinline__ float bf2f(unsigned short b) {
  return __uint_as_float(((uint32_t)b) << 16);
}
// packed f32x2 -> bf16x2 (D[15:0]=bf16(a), D[31:16]=bf16(b))
__device__ __forceinline__ uint32_t cvt_pk_bf16(float a, float b) {
  uint32_t r;
  asm("v_cvt_pk_bf16_f32 %0, %1, %2" : "=v"(r) : "v"(a), "v"(b));
  return r;
}
// MFMA with A pinned in AGPRs (asm keeps W out of the VGPR budget).
__device__ __forceinline__ void mfma_a(f32x4& acc, const bf16x8& a, const bf16x8& b) {
  asm("v_mfma_f32_16x16x32_bf16 %0, %1, %2, %0" : "+v"(acc) : "a"(a), "v"(b));
}

__global__ __launch_bounds__(256)
__attribute__((amdgpu_waves_per_eu(4, 4)))
void rnn_kernel(
    const float* __restrict__ x,
    const float* __restrict__ rec_w,
    const float* __restrict__ rec_b,
    const float* __restrict__ inp_w,
    const float* __restrict__ out_w,
    const float* __restrict__ mem_w,
    float* __restrict__ out) {
  __shared__ Smem sm;
  const int t = threadIdx.x;
  const int m = blockIdx.x;
  const int w = t >> 6;          // wave 0..3
  const int lane = t & 63;
  const int n = lane & 15;       // A-row / B-col / C-col index within tile
  const int kg = lane >> 4;      // k-group (0..3)
  const int c = n & 3;           // cond id
  const int t2sel = n >> 3;      // owned M-tile (0: rows +0..15, 1: +16..31)
  const int lohalf = (n >> 2) & 1;  // 0 = hi-fragment writer, 1 = lo writer

  // step keys
  if (t < 250) {
    int p = t / 50, s = t - p * 50;
    uint2 pk = threefry(0u, 42u, 0u, (uint32_t)p);
    sm.skeys[t] = threefry(pk.x, pk.y, 0u, (uint32_t)s);
  }
  // zero the fragment buffer: exactly 4KB = 256 threads x 16B
  {
    uint4* bz = reinterpret_cast<uint4*>(&sm.bfrag[0][0][0][0][0]);
    bz[t] = make_uint4(0u, 0u, 0u, 0u);
  }

  // --- W fragments: whiA/wloA (AGPR-destined), wlo3 (VGPR, builtin user).
  // row = 32w+16*t2+n, k = 32q+8kg+e.
  bf16x8 whiA[2][4], wloA[2][3], wlo3[2];
  #pragma unroll
  for (int t2 = 0; t2 < 2; ++t2) {
    const int rowA = 32 * w + 16 * t2 + n;
    const float* gp = rec_w + (size_t)m * 16384 + (size_t)rowA * 128 + 8 * kg;
    #pragma unroll
    for (int q = 0; q < 4; ++q) {
      float4 f0 = *reinterpret_cast<const float4*>(gp + 32 * q);
      float4 f1 = *reinterpret_cast<const float4*>(gp + 32 * q + 4);
      float fv[8] = {f0.x, f0.y, f0.z, f0.w, f1.x, f1.y, f1.z, f1.w};
      bf16x8 vh, vl;
      #pragma unroll
      for (int e = 0; e < 8; ++e) {
        unsigned short hb = f2bf(fv[e]);
        vh[e] = (short)hb;
        vl[e] = (short)f2bf(fv[e] - bf2f(hb));
      }
      whiA[t2][q] = vh;
      if (q < 3) wloA[t2][q] = vl; else wlo3[t2] = vl;
    }
  }

  // per-lane x scalars (cond = c)
  const float xs0 = x[c * 4 + 0], xs1 = x[c * 4 + 1];
  const float xt0 = x[c * 4 + 2], xt1 = x[c * 4 + 3];

  // owned rows: rowU..rowU+3 (cond c)
  const int rowU = 32 * w + 4 * kg + 16 * t2sel;

  float rr[4] = {0.f, 0.f, 0.f, 0.f};
  float rs[4];

  __syncthreads();

  const uint32_t njbase = (uint32_t)(m * 128 + 32 * w + (lane & 31));

  for (int ph = 0; ph < 5; ++ph) {
    // ccm = (bias + input drive) for owned rows, hi lanes only (seeds C-init,
    // so the hi+lo column-pair sum carries cc exactly once).
    f32x4 ccv;
    {
      float4 b4 = *reinterpret_cast<const float4*>(&rec_b[(size_t)m * 128 + rowU]);
      float cc[4] = {b4.x, b4.y, b4.z, b4.w};
      if (ph == 1 || ph == 3) {
        const float xa = (ph == 1) ? xs0 : xt0;
        const float xb = (ph == 1) ? xs1 : xt1;
        const float* ip = inp_w + ((size_t)m * 128 + rowU) * 2;
        float4 iA = *reinterpret_cast<const float4*>(ip);
        float4 iB = *reinterpret_cast<const float4*>(ip + 4);
        cc[0] += iA.x * xa + iA.y * xb;
        cc[1] += iA.z * xa + iA.w * xb;
        cc[2] += iB.x * xa + iB.y * xb;
        cc[3] += iB.z * xa + iB.w * xb;
      }
      #pragma unroll
      for (int k = 0; k < 4; ++k) ccv[k] = lohalf ? 0.f : cc[k];
    }
    const bool phD = (ph == 2), phR = (ph == 4);
    #pragma unroll
    for (int k = 0; k < 4; ++k) rs[k] = 0.f;

    for (int sp = 0; sp < 25; ++sp) {
      // noise (0.02-scaled): lane -> (row = lane&31, substep = lane>>5)
      {
        uint2 key = sm.skeys[ph * 50 + 2 * sp + (lane >> 5)];
        uint2 bb = threefry(key.x, key.y, 0u, njbase);
        sm.nbuf[lane >> 5][32 * w + (lane & 31)] = 0.02f * unit_from_bits(bb.x ^ bb.y);
      }

      #pragma unroll
      for (int sub = 0; sub < 2; ++sub) {
        // --- B fragments: lanes n>=8 read col n&7 -> acc cols 8-15 mirror 0-7
        bf16x8 B[4];
        #pragma unroll
        for (int q = 0; q < 4; ++q)
          B[q] = *reinterpret_cast<const bf16x8*>(&sm.bfrag[sub][q][kg][n & 7][0]);

        // --- MFMA: acc{t2} = ccv + (Whi+Wlo) @ B.
        // asm MFMAs (A from AGPR) chain into a final builtin (A=wlo3, VGPR)
        // so the compiler handles the MFMA->VALU read hazard after the chain.
        f32x4 acc0 = ccv, acc1 = ccv;
        #pragma unroll
        for (int q = 0; q < 4; ++q) mfma_a(acc0, whiA[0][q], B[q]);
        #pragma unroll
        for (int q = 0; q < 3; ++q) mfma_a(acc0, wloA[0][q], B[q]);
        acc0 = __builtin_amdgcn_mfma_f32_16x16x32_bf16(wlo3[0], B[3], acc0, 0, 0, 0);
        #pragma unroll
        for (int q = 0; q < 4; ++q) mfma_a(acc1, whiA[1][q], B[q]);
        #pragma unroll
        for (int q = 0; q < 3; ++q) mfma_a(acc1, wloA[1][q], B[q]);
        acc1 = __builtin_amdgcn_mfma_f32_16x16x32_bf16(wlo3[1], B[3], acc1, 0, 0, 0);

        // --- select own tile's acc; pre = col_c + col_{c^4} (carries cc once)
        float4 nz4 = *reinterpret_cast<const float4*>(&sm.nbuf[sub][rowU]);
        float nzv[4] = {nz4.x, nz4.y, nz4.z, nz4.w};
        #pragma unroll
        for (int k = 0; k < 4; ++k) {
          float aS = t2sel ? acc1[k] : acc0[k];
          float pre = aS + __shfl_xor(aS, 4, 64);
          float rl = fmaxf(pre, 0.f);
          rr[k] = fmaf(0.8f, rr[k], fmaf(0.2f, rl, nzv[k]));
        }
        if ((phD && ((sub == 0 && sp >= 13) || (sub == 1 && sp >= 12))) || phR) {
          #pragma unroll
          for (int k = 0; k < 4; ++k) rs[k] += rr[k];
        }

        // --- split & write next-step fragment: every lane writes one uint2.
        {
          const int kgw = 2 * t2sel + (kg >> 1);
          const int e0 = 4 * (kg & 1);
          const int col = c + 4 * lohalf;
          uint32_t h0 = cvt_pk_bf16(rr[0], rr[1]);
          uint32_t h1 = cvt_pk_bf16(rr[2], rr[3]);
          uint2 pk2;
          if (!lohalf) {
            pk2 = make_uint2(h0, h1);
          } else {
            float l0 = rr[0] - __uint_as_float(h0 << 16);
            float l1 = rr[1] - __uint_as_float(h0 & 0xffff0000u);
            float l2 = rr[2] - __uint_as_float(h1 << 16);
            float l3 = rr[3] - __uint_as_float(h1 & 0xffff0000u);
            pk2 = make_uint2(cvt_pk_bf16(l0, l1), cvt_pk_bf16(l2, l3));
          }
          *reinterpret_cast<uint2*>(&sm.bfrag[sub ^ 1][w][kgw][col][e0]) = pk2;
        }
        __syncthreads();
      }
    }

    // --- phase-end projection (linear => project accumulated sums once)
    if (ph == 2 || ph == 4) {
      const float* pw = (ph == 2) ? mem_w : out_w;
      const float denom = (ph == 2) ? 25.0f : 50.0f;
      const int sel = (ph == 2) ? 0 : 1;
      float part[2];
      #pragma unroll
      for (int o = 0; o < 2; ++o) {
        float4 w4 = *reinterpret_cast<const float4*>(&pw[((size_t)m * 2 + o) * 128 + rowU]);
        part[o] = w4.x * rs[0] + w4.y * rs[1] + w4.z * rs[2] + w4.w * rs[3];
      }
      // reduce: xor8 merges t2 partners; xor16/32 merge kg. n&7 classes stay
      // separate, so hi/lo duplicate lanes never double-count.
      #pragma unroll
      for (int o = 0; o < 2; ++o) {
        part[o] += __shfl_xor(part[o], 8, 64);
        part[o] += __shfl_xor(part[o], 16, 64);
        part[o] += __shfl_xor(part[o], 32, 64);
      }
      if (lane < 4) {
        sm.red[w][lane][0] = part[0];
        sm.red[w][lane][1] = part[1];
      }
      __syncthreads();
      if (t < 8) {
        int a = t >> 1, o = t & 1;
        float v = sm.red[0][a][o] + sm.red[1][a][o] + sm.red[2][a][o] + sm.red[3][a][o];
        out[(((size_t)sel * 4 + a) * 2048 + m) * 2 + o] = v / denom;
      }
      __syncthreads();
    }
  }
}

extern "C" void kernel_launch(void* const* d_in, const int* in_sizes, int n_in,
                              void* d_out, int out_size, void* d_ws, size_t ws_size,
                              hipStream_t stream) {
  (void)in_sizes; (void)n_in; (void)d_ws; (void)ws_size; (void)out_size;
  const float* x     = (const float*)d_in[0];
  const float* rec_w = (const float*)d_in[1];
  const float* rec_b = (const float*)d_in[2];
  const float* inp_w = (const float*)d_in[3];
  const float* out_w = (const float*)d_in[4];
  const float* mem_w = (const float*)d_in[5];
  rnn_kernel<<<2048, 256, 0, stream>>>(x, rec_w, rec_b, inp_w, out_w, mem_w, (float*)d_out);
}

// Round 9
// 500.095 us; speedup vs baseline: 1.0802x; 1.0802x over previous
//
#include <hip/hip_runtime.h>
#include <stdint.h>

// RNN ensemble: M=2048 models, N=128, A=4 conds, 5 phases x 50 steps.
// Block = 1 model, 4 waves. Wave w owns rows 32w..32w+31 (2 M-tiles).
// pre[128x4] = W @ r via mfma_f32_16x16x32_bf16, hi/lo bf16 split:
//   B cols 0-3 = rhi (4 conds), cols 4-7 = rlo; chains (Whi then Wlo)@B
//   => comb = col_c + col_{c^4} (shfl_xor 4) = cc + W@rhi + W@rlo.
// R9: ALL 16 W fragments pinned in AGPRs (exactly 64 AGPR) via all-asm MFMA;
// first MFMA per chain is 4-operand D = A*B + ccv (no acc-init movs); acc0/
// acc1 chains interleaved for MFMA ILP. Inline-asm MFMA is invisible to the
// compiler hazard recognizer, so the MFMA->VALU/DS read hazard is covered by
// the threefry block (sub=0, ~70 instrs) or explicit s_nops (sub=1).
// Target: 64 VGPR + 64 AGPR = 128/wave -> 4 waves/SIMD.

typedef __attribute__((ext_vector_type(8))) short bf16x8;
typedef __attribute__((ext_vector_type(4))) float f32x4;

struct __align__(16) Smem {
  unsigned short bfrag[2][4][4][8][8]; // [parity][q][kg][col][e] bf16, 4KB
  float nbuf[2][128];                  // [substep][row] 0.02-scaled noise, 1KB
  uint2 skeys[250];
  float red[4][4][2];                  // [wave][cond][o]
};

__device__ __forceinline__ void tfround(uint32_t& x0, uint32_t& x1, const int r) {
  x0 += x1;
  x1 = (x1 << r) | (x1 >> (32 - r));
  x1 ^= x0;
}

// JAX threefry2x32 (20 rounds)
__device__ __forceinline__ uint2 threefry(uint32_t k0, uint32_t k1, uint32_t c0, uint32_t c1) {
  uint32_t k2 = k0 ^ k1 ^ 0x1BD11BDAu;
  uint32_t x0 = c0 + k0, x1 = c1 + k1;
  tfround(x0,x1,13); tfround(x0,x1,15); tfround(x0,x1,26); tfround(x0,x1,6);
  x0 += k1; x1 += k2 + 1u;
  tfround(x0,x1,17); tfround(x0,x1,29); tfround(x0,x1,16); tfround(x0,x1,24);
  x0 += k2; x1 += k0 + 2u;
  tfround(x0,x1,13); tfround(x0,x1,15); tfround(x0,x1,26); tfround(x0,x1,6);
  x0 += k0; x1 += k1 + 3u;
  tfround(x0,x1,17); tfround(x0,x1,29); tfround(x0,x1,16); tfround(x0,x1,24);
  x0 += k1; x1 += k2 + 4u;
  tfround(x0,x1,13); tfround(x0,x1,15); tfround(x0,x1,26); tfround(x0,x1,6);
  x0 += k2; x1 += k0 + 5u;
  return make_uint2(x0, x1);
}

__device__ __forceinline__ float unit_from_bits(uint32_t bits) {
  return __uint_as_float((bits >> 9) | 0x3f800000u) - 1.0f;
}

__device__ __forceinline__ unsigned short f2bf(float f) {
  uint32_t u = __float_as_uint(f);
  uint32_t r = u + 0x7fffu + ((u >> 16) & 1u);   // RNE (non-NaN inputs)
  return (unsigned short)(r >> 16);
}
__device__ __forceinline__ float bf2f(unsigned short b) {
  return __uint_as_float(((uint32_t)b) << 16);
}
// packed f32x2 -> bf16x2 (D[15:0]=bf16(a), D[31:16]=bf16(b))
__device__ __forceinline__ uint32_t cvt_pk_bf16(float a, float b) {
  uint32_t r;
  asm("v_cvt_pk_bf16_f32 %0, %1, %2" : "=v"(r) : "v"(a), "v"(b));
  return r;
}
// MFMA accumulate in place, A from AGPR.
__device__ __forceinline__ void mfma_aa(f32x4& acc, const bf16x8& a, const bf16x8& b) {
  asm("v_mfma_f32_16x16x32_bf16 %0, %1, %2, %0" : "+v"(acc) : "a"(a), "v"(b));
}
// MFMA chain head: D = A*B + C with D != any input (no acc-init mov).
__device__ __forceinline__ f32x4 mfma_init(const bf16x8& a, const bf16x8& b, const f32x4& c) {
  f32x4 d;
  asm("v_mfma_f32_16x16x32_bf16 %0, %1, %2, %3" : "=&v"(d) : "a"(a), "v"(b), "v"(c));
  return d;
}

__global__ __launch_bounds__(256)
__attribute__((amdgpu_waves_per_eu(4, 4)))
void rnn_kernel(
    const float* __restrict__ x,
    const float* __restrict__ rec_w,
    const float* __restrict__ rec_b,
    const float* __restrict__ inp_w,
    const float* __restrict__ out_w,
    const float* __restrict__ mem_w,
    float* __restrict__ out) {
  __shared__ Smem sm;
  const int t = threadIdx.x;
  const int m = blockIdx.x;
  const int w = t >> 6;          // wave 0..3
  const int lane = t & 63;
  const int n = lane & 15;       // A-row / B-col / C-col index within tile
  const int kg = lane >> 4;      // k-group (0..3)
  const int c = n & 3;           // cond id
  const int t2sel = n >> 3;      // owned M-tile (0: rows +0..15, 1: +16..31)
  const int lohalf = (n >> 2) & 1;  // 0 = hi-fragment writer, 1 = lo writer

  // step keys
  if (t < 250) {
    int p = t / 50, s = t - p * 50;
    uint2 pk = threefry(0u, 42u, 0u, (uint32_t)p);
    sm.skeys[t] = threefry(pk.x, pk.y, 0u, (uint32_t)s);
  }
  // zero the fragment buffer: exactly 4KB = 256 threads x 16B
  {
    uint4* bz = reinterpret_cast<uint4*>(&sm.bfrag[0][0][0][0][0]);
    bz[t] = make_uint4(0u, 0u, 0u, 0u);
  }

  // --- W fragments (all AGPR-destined): row = 32w+16*t2+n, k = 32q+8kg+e
  bf16x8 whiA[2][4], wloA[2][4];
  #pragma unroll
  for (int t2 = 0; t2 < 2; ++t2) {
    const int rowA = 32 * w + 16 * t2 + n;
    const float* gp = rec_w + (size_t)m * 16384 + (size_t)rowA * 128 + 8 * kg;
    #pragma unroll
    for (int q = 0; q < 4; ++q) {
      float4 f0 = *reinterpret_cast<const float4*>(gp + 32 * q);
      float4 f1 = *reinterpret_cast<const float4*>(gp + 32 * q + 4);
      float fv[8] = {f0.x, f0.y, f0.z, f0.w, f1.x, f1.y, f1.z, f1.w};
      bf16x8 vh, vl;
      #pragma unroll
      for (int e = 0; e < 8; ++e) {
        unsigned short hb = f2bf(fv[e]);
        vh[e] = (short)hb;
        vl[e] = (short)f2bf(fv[e] - bf2f(hb));
      }
      whiA[t2][q] = vh;
      wloA[t2][q] = vl;
    }
  }

  // per-lane x scalars (cond = c)
  const float xs0 = x[c * 4 + 0], xs1 = x[c * 4 + 1];
  const float xt0 = x[c * 4 + 2], xt1 = x[c * 4 + 3];

  // owned rows: rowU..rowU+3 (cond c)
  const int rowU = 32 * w + 4 * kg + 16 * t2sel;

  float rr[4] = {0.f, 0.f, 0.f, 0.f};
  float rs[4];

  __syncthreads();

  const uint32_t njbase = (uint32_t)(m * 128 + 32 * w + (lane & 31));

  for (int ph = 0; ph < 5; ++ph) {
    // ccv = (bias + input drive) for owned rows, hi lanes only (seeds the
    // MFMA chain head, so the hi+lo column-pair sum carries cc exactly once).
    f32x4 ccv;
    {
      float4 b4 = *reinterpret_cast<const float4*>(&rec_b[(size_t)m * 128 + rowU]);
      float cc[4] = {b4.x, b4.y, b4.z, b4.w};
      if (ph == 1 || ph == 3) {
        const float xa = (ph == 1) ? xs0 : xt0;
        const float xb = (ph == 1) ? xs1 : xt1;
        const float* ip = inp_w + ((size_t)m * 128 + rowU) * 2;
        float4 iA = *reinterpret_cast<const float4*>(ip);
        float4 iB = *reinterpret_cast<const float4*>(ip + 4);
        cc[0] += iA.x * xa + iA.y * xb;
        cc[1] += iA.z * xa + iA.w * xb;
        cc[2] += iB.x * xa + iB.y * xb;
        cc[3] += iB.z * xa + iB.w * xb;
      }
      #pragma unroll
      for (int k = 0; k < 4; ++k) ccv[k] = lohalf ? 0.f : cc[k];
    }
    const bool phD = (ph == 2), phR = (ph == 4);
    #pragma unroll
    for (int k = 0; k < 4; ++k) rs[k] = 0.f;

    for (int sp = 0; sp < 25; ++sp) {
      #pragma unroll
      for (int sub = 0; sub < 2; ++sub) {
        // --- B fragments: lanes n>=8 read col n&7 -> acc cols 8-15 mirror 0-7
        bf16x8 B[4];
        #pragma unroll
        for (int q = 0; q < 4; ++q)
          B[q] = *reinterpret_cast<const bf16x8*>(&sm.bfrag[sub][q][kg][n & 7][0]);

        // --- MFMA: acc{t2} = ccv + (Whi+Wlo) @ B, chains interleaved
        f32x4 acc0 = mfma_init(whiA[0][0], B[0], ccv);
        f32x4 acc1 = mfma_init(whiA[1][0], B[0], ccv);
        #pragma unroll
        for (int q = 1; q < 4; ++q) {
          mfma_aa(acc0, whiA[0][q], B[q]);
          mfma_aa(acc1, whiA[1][q], B[q]);
        }
        #pragma unroll
        for (int q = 0; q < 4; ++q) {
          mfma_aa(acc0, wloA[0][q], B[q]);
          mfma_aa(acc1, wloA[1][q], B[q]);
        }

        if (sub == 0) {
          // threefry fills the MFMA->read hazard window (~70 VALU instrs) and
          // overlaps the MFMA pipe. nbuf is wave-local; DS ops within a wave
          // are in-order, so the b128 reads below see these writes.
          uint2 key = sm.skeys[ph * 50 + 2 * sp + (lane >> 5)];
          uint2 bb = threefry(key.x, key.y, 0u, njbase);
          sm.nbuf[lane >> 5][32 * w + (lane & 31)] = 0.02f * unit_from_bits(bb.x ^ bb.y);
        } else {
          // inline-asm MFMA is invisible to the hazard recognizer: guard the
          // D->VALU/DS read with explicit wait states.
          asm volatile("s_nop 7\n\ts_nop 7\n\ts_nop 3" ::);
        }

        // --- select own tile's acc; pre = col_c + col_{c^4} (carries cc once)
        float4 nz4 = *reinterpret_cast<const float4*>(&sm.nbuf[sub][rowU]);
        float nzv[4] = {nz4.x, nz4.y, nz4.z, nz4.w};
        #pragma unroll
        for (int k = 0; k < 4; ++k) {
          float aS = t2sel ? acc1[k] : acc0[k];
          float pre = aS + __shfl_xor(aS, 4, 64);
          float rl = fmaxf(pre, 0.f);
          rr[k] = fmaf(0.8f, rr[k], fmaf(0.2f, rl, nzv[k]));
        }
        if ((phD && ((sub == 0 && sp >= 13) || (sub == 1 && sp >= 12))) || phR) {
          #pragma unroll
          for (int k = 0; k < 4; ++k) rs[k] += rr[k];
        }

        // --- split & write next-step fragment: every lane writes one uint2.
        {
          const int kgw = 2 * t2sel + (kg >> 1);
          const int e0 = 4 * (kg & 1);
          const int col = c + 4 * lohalf;
          uint32_t h0 = cvt_pk_bf16(rr[0], rr[1]);
          uint32_t h1 = cvt_pk_bf16(rr[2], rr[3]);
          uint2 pk2;
          if (!lohalf) {
            pk2 = make_uint2(h0, h1);
          } else {
            float l0 = rr[0] - __uint_as_float(h0 << 16);
            float l1 = rr[1] - __uint_as_float(h0 & 0xffff0000u);
            float l2 = rr[2] - __uint_as_float(h1 << 16);
            float l3 = rr[3] - __uint_as_float(h1 & 0xffff0000u);
            pk2 = make_uint2(cvt_pk_bf16(l0, l1), cvt_pk_bf16(l2, l3));
          }
          *reinterpret_cast<uint2*>(&sm.bfrag[sub ^ 1][w][kgw][col][e0]) = pk2;
        }
        __syncthreads();
      }
    }

    // --- phase-end projection (linear => project accumulated sums once)
    if (ph == 2 || ph == 4) {
      const float* pw = (ph == 2) ? mem_w : out_w;
      const float denom = (ph == 2) ? 25.0f : 50.0f;
      const int sel = (ph == 2) ? 0 : 1;
      float part[2];
      #pragma unroll
      for (int o = 0; o < 2; ++o) {
        float4 w4 = *reinterpret_cast<const float4*>(&pw[((size_t)m * 2 + o) * 128 + rowU]);
        part[o] = w4.x * rs[0] + w4.y * rs[1] + w4.z * rs[2] + w4.w * rs[3];
      }
      // reduce: xor8 merges t2 partners; xor16/32 merge kg. n&7 classes stay
      // separate, so hi/lo duplicate lanes never double-count.
      #pragma unroll
      for (int o = 0; o < 2; ++o) {
        part[o] += __shfl_xor(part[o], 8, 64);
        part[o] += __shfl_xor(part[o], 16, 64);
        part[o] += __shfl_xor(part[o], 32, 64);
      }
      if (lane < 4) {
        sm.red[w][lane][0] = part[0];
        sm.red[w][lane][1] = part[1];
      }
      __syncthreads();
      if (t < 8) {
        int a = t >> 1, o = t & 1;
        float v = sm.red[0][a][o] + sm.red[1][a][o] + sm.red[2][a][o] + sm.red[3][a][o];
        out[(((size_t)sel * 4 + a) * 2048 + m) * 2 + o] = v / denom;
      }
      __syncthreads();
    }
  }
}

extern "C" void kernel_launch(void* const* d_in, const int* in_sizes, int n_in,
                              void* d_out, int out_size, void* d_ws, size_t ws_size,
                              hipStream_t stream) {
  (void)in_sizes; (void)n_in; (void)d_ws; (void)ws_size; (void)out_size;
  const float* x     = (const float*)d_in[0];
  const float* rec_w = (const float*)d_in[1];
  const float* rec_b = (const float*)d_in[2];
  const float* inp_w = (const float*)d_in[3];
  const float* out_w = (const float*)d_in[4];
  const float* mem_w = (const float*)d_in[5];
  rnn_kernel<<<2048, 256, 0, stream>>>(x, rec_w, rec_b, inp_w, out_w, mem_w, (float*)d_out);
}